// Round 3
// baseline (199.142 us; speedup 1.0000x reference)
//
#include <hip/hip_runtime.h>

// UnitaryBranching on MI355X.
// maps[n] = T[prefix] @ T[suffix] over a 127-entry binary-product table of
// ext = [P0^T, P1^T, I, I]; table+maps in bf16 MFMA (0.48 threshold, ~18x margin).
// expm: f32, Paterson-Stockmeyer deg-11 Taylor + 6 squarings (11 matmuls),
// packed v_pk_fma_f32. steps[i][j] = 24 - 2*cpl, exact, fused with expm.

#define NPOS 4096
#define TLEN 12

typedef __attribute__((ext_vector_type(8))) short short8;
typedef __attribute__((ext_vector_type(4))) float f32x4;
typedef __attribute__((ext_vector_type(2))) float f32x2;

__device__ __forceinline__ unsigned short f2bf(float f) {
  union { float f; unsigned u; } v; v.f = f;
  unsigned r = v.u + 0x7fffu + ((v.u >> 16) & 1u);  // RNE
  return (unsigned short)(r >> 16);
}

// acc(4x4 as f32x2[4][2]) += P[r0..r0+3][:] @ B[:][c0..c0+3], packed-f32 FMA.
// Both operands [64][68] f32 (272B rows: 16B-aligned float4, banks spread).
__device__ __forceinline__ void mm64p(const float (*P)[68], const float (*B)[68],
                                      f32x2 acc[4][2], int r0, int c0) {
#pragma unroll 4
  for (int k0 = 0; k0 < 64; k0 += 4) {
    float a[4][4];
#pragma unroll
    for (int i = 0; i < 4; ++i) {
      const float4 t4 = *reinterpret_cast<const float4*>(&P[r0 + i][k0]);
      a[i][0] = t4.x; a[i][1] = t4.y; a[i][2] = t4.z; a[i][3] = t4.w;
    }
#pragma unroll
    for (int kk = 0; kk < 4; ++kk) {
      const float4 bv = *reinterpret_cast<const float4*>(&B[k0 + kk][c0]);
      const f32x2 lo = {bv.x, bv.y}, hi = {bv.z, bv.w};
#pragma unroll
      for (int i = 0; i < 4; ++i) {
        acc[i][0] += a[i][kk] * lo;
        acc[i][1] += a[i][kk] * hi;
      }
    }
  }
}

__device__ __forceinline__ float step_val(unsigned a, unsigned b) {
  const unsigned x = a ^ b;
  const int cp = x ? (__builtin_clz(x) >> 1) : TLEN;
  return (float)(2 * TLEN - 2 * cp);
}

// blocks 0,1: expm (PS deg-11 + 6 squarings, f32); blocks 2..: steps tiles
// (write-bound, fills the other 254 CUs while expm runs).
__global__ __launch_bounds__(256) void expm_steps_kernel(
    const float* __restrict__ raw, const unsigned* __restrict__ keys,
    unsigned short* __restrict__ tabR, unsigned short* __restrict__ tabT,
    float* __restrict__ steps_out) {
  __shared__ float P[64][68];
  __shared__ float Bs[64][68];
  const int t = threadIdx.x;

  if (blockIdx.x >= 2) {  // ---- steps ----
    const int b = (int)blockIdx.x - 2;
    const int i = b >> 2;
    const int j0 = ((b & 3) << 10) | (t << 2);
    const unsigned ki = keys[i];
    const uint4 kj = *reinterpret_cast<const uint4*>(&keys[j0]);
    float4 r;
    r.x = step_val(ki, kj.x);
    r.y = step_val(ki, kj.y);
    r.z = step_val(ki, kj.z);
    r.w = step_val(ki, kj.w);
    *reinterpret_cast<float4*>(&steps_out[(size_t)i * NPOS + j0]) = r;
    return;
  }

  // ---- expm for matrix d: E = expm(H), H = raw_d - raw_d^T, A = H/2^6 ----
  const int d = blockIdx.x;
  const int r0 = (t >> 4) << 2, c0 = (t & 15) << 2;
  const float* R = raw + d * 4096;
  float a_[4][4], a2_[4][4], e_[4][4];
  f32x2 acc[4][2];
#define ZACC { _Pragma("unroll") for (int i = 0; i < 4; ++i) { acc[i][0] = f32x2{0.f,0.f}; acc[i][1] = f32x2{0.f,0.f}; } }
#define GETACC(i, j) ((j) < 2 ? acc[i][0][j] : acc[i][1][(j)-2])

#pragma unroll
  for (int i = 0; i < 4; ++i)
#pragma unroll
    for (int j = 0; j < 4; ++j)
      a_[i][j] = (R[(r0 + i) * 64 + c0 + j] - R[(c0 + j) * 64 + r0 + i]) * (1.0f / 64.0f);
#pragma unroll
  for (int i = 0; i < 4; ++i) {
    const float4 v = make_float4(a_[i][0], a_[i][1], a_[i][2], a_[i][3]);
    *reinterpret_cast<float4*>(&P[r0 + i][c0]) = v;   // P = A
    *reinterpret_cast<float4*>(&Bs[r0 + i][c0]) = v;  // Bs = A
  }
  __syncthreads();

  // A2 = A @ A
  ZACC; mm64p(P, Bs, acc, r0, c0);
  __syncthreads();
#pragma unroll
  for (int i = 0; i < 4; ++i) {
#pragma unroll
    for (int j = 0; j < 4; ++j) a2_[i][j] = GETACC(i, j);
    *reinterpret_cast<float4*>(&Bs[r0 + i][c0]) =
        make_float4(a2_[i][0], a2_[i][1], a2_[i][2], a2_[i][3]);  // Bs = A2
  }
  __syncthreads();

  // A3 = A @ A2 -> Bs; P = Q0 = c9 I + c10 A + c11 A2
  ZACC; mm64p(P, Bs, acc, r0, c0);
  __syncthreads();
#pragma unroll
  for (int i = 0; i < 4; ++i) {
    float q[4];
#pragma unroll
    for (int j = 0; j < 4; ++j) {
      const float id = (r0 + i == c0 + j) ? 1.0f : 0.0f;
      q[j] = (1.0f / 362880.0f) * id + (1.0f / 3628800.0f) * a_[i][j] +
             (1.0f / 39916800.0f) * a2_[i][j];
    }
    *reinterpret_cast<float4*>(&Bs[r0 + i][c0]) =
        make_float4(GETACC(i, 0), GETACC(i, 1), GETACC(i, 2), GETACC(i, 3));  // Bs = A3
    *reinterpret_cast<float4*>(&P[r0 + i][c0]) = make_float4(q[0], q[1], q[2], q[3]);
  }
  __syncthreads();

  // 3 Horner steps: Q = Q @ A3 + (ck0 I + ck1 A + ck2 A2)
  const float C[3][3] = {{1.0f / 720.0f, 1.0f / 5040.0f, 1.0f / 40320.0f},
                         {1.0f / 6.0f, 1.0f / 24.0f, 1.0f / 120.0f},
                         {1.0f, 1.0f, 0.5f}};
#pragma unroll
  for (int h = 0; h < 3; ++h) {
    ZACC; mm64p(P, Bs, acc, r0, c0);
    __syncthreads();
#pragma unroll
    for (int i = 0; i < 4; ++i) {
      float q[4];
#pragma unroll
      for (int j = 0; j < 4; ++j) {
        const float id = (r0 + i == c0 + j) ? 1.0f : 0.0f;
        q[j] = GETACC(i, j) + C[h][0] * id + C[h][1] * a_[i][j] + C[h][2] * a2_[i][j];
      }
      const float4 v = make_float4(q[0], q[1], q[2], q[3]);
      *reinterpret_cast<float4*>(&P[r0 + i][c0]) = v;
      if (h == 2) *reinterpret_cast<float4*>(&Bs[r0 + i][c0]) = v;  // E into both
    }
    __syncthreads();
  }

  // 6 squarings: E = E @ E
  for (int s = 0; s < 6; ++s) {
    ZACC; mm64p(P, Bs, acc, r0, c0);
    __syncthreads();
#pragma unroll
    for (int i = 0; i < 4; ++i)
#pragma unroll
      for (int j = 0; j < 4; ++j) e_[i][j] = GETACC(i, j);
    if (s < 5) {
#pragma unroll
      for (int i = 0; i < 4; ++i) {
        const float4 v = make_float4(e_[i][0], e_[i][1], e_[i][2], e_[i][3]);
        *reinterpret_cast<float4*>(&P[r0 + i][c0]) = v;
        *reinterpret_cast<float4*>(&Bs[r0 + i][c0]) = v;
      }
      __syncthreads();
    }
  }

  // ext[d] = E^T: tabR[1+d] = E^T row-major (A-role); tabT[1+d] = E (B-role)
  unsigned short* oR = tabR + (size_t)(1 + d) * 4096;
  unsigned short* oT = tabT + (size_t)(1 + d) * 4096;
#pragma unroll
  for (int i = 0; i < 4; ++i)
#pragma unroll
    for (int j = 0; j < 4; ++j) {
      const unsigned short v = f2bf(e_[i][j]);
      oR[(c0 + j) * 64 + (r0 + i)] = v;
      oT[(r0 + i) * 64 + (c0 + j)] = v;
    }
  if (d == 0) {
#pragma unroll
    for (int i = 0; i < 16; ++i) {
      const int idx = (i << 8) | t;
      const int r = idx >> 6, c = idx & 63;
      const unsigned short v = (r == c) ? (unsigned short)0x3F80 : (unsigned short)0;
      tabR[idx] = v;
      tabT[idx] = v;
    }
  }
#undef ZACC
#undef GETACC
}

// MFMA frag helpers: X row-major (A-role), Yt = Y^T row-major (B-role).
// k-map kappa(q,g,b)=32q+8g+b applied identically to A and B (layout-safe).
__device__ __forceinline__ void mfma64(const unsigned short* __restrict__ X,
                                       const unsigned short* __restrict__ Yt,
                                       f32x4 acc[4], int wv, int l) {
  const int row = l & 15, g = l >> 4;
  short8 a[2], b[4][2];
#pragma unroll
  for (int q = 0; q < 2; ++q)
    a[q] = *reinterpret_cast<const short8*>(X + (((16 * wv + row) << 6) | (q << 5) | (g << 3)));
#pragma unroll
  for (int c = 0; c < 4; ++c)
#pragma unroll
    for (int q = 0; q < 2; ++q)
      b[c][q] = *reinterpret_cast<const short8*>(Yt + (((16 * c + row) << 6) | (q << 5) | (g << 3)));
#pragma unroll
  for (int c = 0; c < 4; ++c) {
    acc[c] = __builtin_amdgcn_mfma_f32_16x16x32_bf16(a[0], b[c][0], acc[c], 0, 0, 0);
    acc[c] = __builtin_amdgcn_mfma_f32_16x16x32_bf16(a[1], b[c][1], acc[c], 0, 0, 0);
  }
}

// One block per table entry e=3..126; chain of (level-1) MFMA products from
// ext[0],ext[1] directly. No cross-block deps, single launch.
__global__ __launch_bounds__(256) void pairs_kernel(unsigned short* __restrict__ tabR,
                                                    unsigned short* __restrict__ tabT) {
  __shared__ unsigned short Tl[64][72];  // 144B rows: 16B-aligned short8
  const int e = 3 + (int)blockIdx.x;
  const int lev = 31 - __clz(e + 1);   // 2..6
  const int v = (e + 1) - (1 << lev);  // digit word
  const int wv = threadIdx.x >> 6, l = threadIdx.x & 63;
  const int row = l & 15, g = l >> 4;

  short8 bT[2][4][2];  // B-frags of both digit matrices, prefetched once
#pragma unroll
  for (int dd = 0; dd < 2; ++dd)
#pragma unroll
    for (int c = 0; c < 4; ++c)
#pragma unroll
      for (int q = 0; q < 2; ++q)
        bT[dd][c][q] = *reinterpret_cast<const short8*>(
            tabT + (size_t)(1 + dd) * 4096 + (((16 * c + row) << 6) | (q << 5) | (g << 3)));

  const int d0 = (v >> (lev - 1)) & 1;
  short8 a[2];
#pragma unroll
  for (int q = 0; q < 2; ++q)
    a[q] = *reinterpret_cast<const short8*>(
        tabR + (size_t)(1 + d0) * 4096 + (((16 * wv + row) << 6) | (q << 5) | (g << 3)));

  f32x4 acc[4] = {f32x4{0,0,0,0}, f32x4{0,0,0,0}, f32x4{0,0,0,0}, f32x4{0,0,0,0}};
  const int d1 = (v >> (lev - 2)) & 1;
#pragma unroll
  for (int c = 0; c < 4; ++c) {
    acc[c] = __builtin_amdgcn_mfma_f32_16x16x32_bf16(a[0], bT[d1][c][0], acc[c], 0, 0, 0);
    acc[c] = __builtin_amdgcn_mfma_f32_16x16x32_bf16(a[1], bT[d1][c][1], acc[c], 0, 0, 0);
  }

  for (int j = 2; j < lev; ++j) {
    const int dj = (v >> (lev - 1 - j)) & 1;
#pragma unroll
    for (int c = 0; c < 4; ++c)
#pragma unroll
      for (int r = 0; r < 4; ++r)
        Tl[16 * wv + 4 * g + r][16 * c + row] = f2bf(acc[c][r]);
    __syncthreads();
#pragma unroll
    for (int q = 0; q < 2; ++q)
      a[q] = *reinterpret_cast<const short8*>(&Tl[16 * wv + row][(q << 5) | (g << 3)]);
    __syncthreads();
#pragma unroll
    for (int c = 0; c < 4; ++c) {
      acc[c] = f32x4{0, 0, 0, 0};
      acc[c] = __builtin_amdgcn_mfma_f32_16x16x32_bf16(a[0], bT[dj][c][0], acc[c], 0, 0, 0);
      acc[c] = __builtin_amdgcn_mfma_f32_16x16x32_bf16(a[1], bT[dj][c][1], acc[c], 0, 0, 0);
    }
  }

  unsigned short* oR = tabR + (size_t)e * 4096;
  unsigned short* oT = tabT + (size_t)e * 4096;
#pragma unroll
  for (int c = 0; c < 4; ++c)
#pragma unroll
    for (int r = 0; r < 4; ++r) {
      const unsigned short val = f2bf(acc[c][r]);
      const int rr = 16 * wv + 4 * g + r, cc = 16 * c + row;
      oR[rr * 64 + cc] = val;
      oT[cc * 64 + rr] = val;
    }
}

// maps[n] = T[prefix] @ T[suffix]; C staged in LDS then written coalesced.
__global__ __launch_bounds__(256) void maps_kernel(const int* __restrict__ pw,
                                                   const unsigned short* __restrict__ tabR,
                                                   const unsigned short* __restrict__ tabT,
                                                   float* __restrict__ out) {
  __shared__ float T[64][68];
  const int n = blockIdx.x;
  const int t = threadIdx.x;
  int v1 = 0, l1 = 0, v2 = 0, l2 = 0;
#pragma unroll
  for (int tt = 0; tt < 6; ++tt) {
    const int w = pw[n * TLEN + tt];
    if (w < 2) { v1 = (v1 << 1) | w; ++l1; }
  }
#pragma unroll
  for (int tt = 6; tt < 12; ++tt) {
    const int w = pw[n * TLEN + tt];
    if (w < 2) { v2 = (v2 << 1) | w; ++l2; }
  }
  const int wv = t >> 6, l = t & 63;
  f32x4 acc[4] = {f32x4{0,0,0,0}, f32x4{0,0,0,0}, f32x4{0,0,0,0}, f32x4{0,0,0,0}};
  mfma64(tabR + (size_t)((1 << l1) - 1 + v1) * 4096,
         tabT + (size_t)((1 << l2) - 1 + v2) * 4096, acc, wv, l);
  const int row = l & 15, g = l >> 4;
#pragma unroll
  for (int c = 0; c < 4; ++c)
#pragma unroll
    for (int r = 0; r < 4; ++r)
      T[16 * wv + 4 * g + r][16 * c + row] = acc[c][r];
  __syncthreads();
  float* O = out + (size_t)n * 4096;
#pragma unroll
  for (int p = 0; p < 4; ++p) {
    const int idx = (p << 8) | t;
    const int rr = idx >> 4, cc = (idx & 15) << 2;
    *reinterpret_cast<float4*>(&O[(rr << 6) | cc]) =
        *reinterpret_cast<const float4*>(&T[rr][cc]);
  }
}

__global__ __launch_bounds__(256) void keys_kernel(const int* __restrict__ pw,
                                                   unsigned* __restrict__ keys) {
  const int n = blockIdx.x * 256 + threadIdx.x;
  unsigned k = 0;
#pragma unroll
  for (int tt = 0; tt < TLEN; ++tt) k = (k << 2) | (unsigned)pw[n * TLEN + tt];
  keys[n] = k << 8;
}

extern "C" void kernel_launch(void* const* d_in, const int* in_sizes, int n_in,
                              void* d_out, int out_size, void* d_ws, size_t ws_size,
                              hipStream_t stream) {
  const float* raw = (const float*)d_in[0];  // (17,64,64) f32
  const int* pw = (const int*)d_in[1];       // (4096,12) i32
  float* out = (float*)d_out;                // maps then steps, f32

  unsigned short* tabR = (unsigned short*)d_ws;        // 127 * 8KB
  unsigned short* tabT = tabR + (size_t)127 * 4096;    // 127 * 8KB
  unsigned* keys = (unsigned*)((char*)d_ws + (4u << 20));

  keys_kernel<<<NPOS / 256, 256, 0, stream>>>(pw, keys);
  expm_steps_kernel<<<2 + NPOS * 4, 256, 0, stream>>>(raw, keys, tabR, tabT,
                                                      out + (size_t)NPOS * 4096);
  pairs_kernel<<<124, 256, 0, stream>>>(tabR, tabT);
  maps_kernel<<<NPOS, 256, 0, stream>>>(pw, tabR, tabT, out);
}